// Round 3
// baseline (371.529 us; speedup 1.0000x reference)
//
#include <hip/hip_runtime.h>
#include <hip/hip_bf16.h>

// out[i][j] = ||x_i - y_j||, x:[4096,256] f32, y:[16384,256] f32, out:[4096,16384] f32
// d2 = x2 + y2 - 2<x,y>; cross term via bf16 MFMA.
// Round 3: NO LDS. MFMA fragments (16-B row-major chunks) load directly from
// the bf16 copies in L2. No barriers, no staging, nontemporal output stores.

using bf16x8 = __attribute__((ext_vector_type(8))) short;
using f32x4  = __attribute__((ext_vector_type(4))) float;

constexpr int NXR = 4096;    // rows of x
constexpr int NYR = 16384;   // rows of y
constexpr int DD  = 256;     // feature dim

constexpr int BT = 128;      // block output tile edge (x-rows and y-rows)

__device__ inline unsigned short f2bf(float f) {
    unsigned int b = __float_as_uint(f);
    b += 0x7FFFu + ((b >> 16) & 1u);   // RNE
    return (unsigned short)(b >> 16);
}

// ---------------- prep: bf16 copies + row norms. One wave per row.
__global__ __launch_bounds__(256) void prep_kernel(const float* __restrict__ x,
                                                   const float* __restrict__ y,
                                                   unsigned short* __restrict__ xb,
                                                   unsigned short* __restrict__ yb,
                                                   float* __restrict__ xn,
                                                   float* __restrict__ yn) {
    const int row  = blockIdx.x * 4 + (threadIdx.x >> 6);
    const int lane = threadIdx.x & 63;
    const bool isx = row < NXR;
    const int r    = isx ? row : row - NXR;
    const float* src = (isx ? x : y) + (size_t)r * DD;
    float4 v = *(const float4*)(src + lane * 4);
    ushort4 u = { f2bf(v.x), f2bf(v.y), f2bf(v.z), f2bf(v.w) };
    unsigned short* dst = (isx ? xb : yb) + (size_t)r * DD;
    *(ushort4*)(dst + lane * 4) = u;
    float s = v.x * v.x + v.y * v.y + v.z * v.z + v.w * v.w;
    #pragma unroll
    for (int off = 32; off > 0; off >>= 1) s += __shfl_down(s, off, 64);
    if (lane == 0) { if (isx) xn[r] = s; else yn[r] = s; }
}

// ---------------- main distance kernel (no LDS)
// MFMA roles: A = y tile (M), B = x tile (N). 16x16x32 bf16.
// A/B fragment: row = lane&15 (+16*i), k = quad*8..+7  -> 16-B contiguous global load.
// D: n(col -> x-row) = lane&15, m(row -> y-col) = quad*4 + reg -> float4 stores along y.
__global__ __launch_bounds__(256, 4) void dist_kernel(const unsigned short* __restrict__ xb,
                                                      const unsigned short* __restrict__ yb,
                                                      const float* __restrict__ xn,
                                                      const float* __restrict__ yn,
                                                      float* __restrict__ out) {
    const int bm = blockIdx.x;          // x tile: 0..31  (fastest -> y-tile shared across XCDs)
    const int bn = blockIdx.y;          // y tile: 0..127
    const int tid  = threadIdx.x;
    const int wave = tid >> 6;          // 0..3; wave tile 64(y) x 64(x)
    const int lane = tid & 63;
    const int quad = lane >> 4;
    const int l15  = lane & 15;
    const int wm   = wave & 1;          // y half
    const int wn   = wave >> 1;         // x half

    const int yr0 = bn * BT + wm * 64;  // y rows (M) base for this wave
    const int xr0 = bm * BT + wn * 64;  // x rows (N) base for this wave

    f32x4 acc[4][4];
    #pragma unroll
    for (int i = 0; i < 4; ++i)
        #pragma unroll
        for (int j = 0; j < 4; ++j)
            acc[i][j] = f32x4{0.f, 0.f, 0.f, 0.f};

    const unsigned short* ya = yb + (size_t)(yr0 + l15) * DD + quad * 8;
    const unsigned short* xa = xb + (size_t)(xr0 + l15) * DD + quad * 8;

    #pragma unroll
    for (int kk = 0; kk < 8; ++kk) {
        const int ko = kk * 32;
        bf16x8 av[4], bv[4];
        #pragma unroll
        for (int i = 0; i < 4; ++i)
            av[i] = *(const bf16x8*)(ya + (size_t)(i * 16) * DD + ko);
        #pragma unroll
        for (int j = 0; j < 4; ++j)
            bv[j] = *(const bf16x8*)(xa + (size_t)(j * 16) * DD + ko);
        #pragma unroll
        for (int i = 0; i < 4; ++i)
            #pragma unroll
            for (int j = 0; j < 4; ++j)
                acc[i][j] = __builtin_amdgcn_mfma_f32_16x16x32_bf16(
                    av[i], bv[j], acc[i][j], 0, 0, 0);
    }

    // ---- epilogue: d = sqrt(max(x2 + y2 - 2*xy, 0)), nontemporal float4 stores along y
    #pragma unroll
    for (int i = 0; i < 4; ++i) {
        const int ycol = yr0 + i * 16 + quad * 4;
        const f32x4 ynv = *(const f32x4*)&yn[ycol];
        #pragma unroll
        for (int j = 0; j < 4; ++j) {
            const int xrow = xr0 + j * 16 + l15;
            const float xv = xn[xrow];
            f32x4 d;
            #pragma unroll
            for (int r = 0; r < 4; ++r)
                d[r] = __builtin_amdgcn_sqrtf(fmaxf(xv + ynv[r] - 2.0f * acc[i][j][r], 0.0f));
            __builtin_nontemporal_store(d, (f32x4*)&out[(size_t)xrow * NYR + ycol]);
        }
    }
}

extern "C" void kernel_launch(void* const* d_in, const int* in_sizes, int n_in,
                              void* d_out, int out_size, void* d_ws, size_t ws_size,
                              hipStream_t stream) {
    const float* x = (const float*)d_in[0];
    const float* y = (const float*)d_in[1];
    float* out = (float*)d_out;

    unsigned short* xb = (unsigned short*)d_ws;
    unsigned short* yb = xb + (size_t)NXR * DD;
    float* xn = (float*)(yb + (size_t)NYR * DD);
    float* yn = xn + NXR;

    prep_kernel<<<(NXR + NYR) / 4, 256, 0, stream>>>(x, y, xb, yb, xn, yn);
    dist_kernel<<<dim3(NXR / BT, NYR / BT), 256, 0, stream>>>(xb, yb, xn, yn, out);
}